// Round 2
// baseline (2330.730 us; speedup 1.0000x reference)
//
#include <hip/hip_runtime.h>
#include <hip/hip_bf16.h>

// Problem constants (from reference setup_inputs)
#define Bc 2
#define Nc 6
#define Cc 128
#define Hc 16
#define Wc 44
#define Dc 64
#define HWc (Hc*Wc)          // 704
#define BNc (Bc*Nc)          // 12
#define NPTS (Bc*Nc*Dc*HWc)  // 540672
#define BEV_W 256
#define BEV_H 256
#define BEV_HW (BEV_W*BEV_H) // 65536

// workspace layout (bytes)
#define OFF_KI   0                         // float Kinv[12][9]
#define OFF_DB   2048                      // float dbins[64]
#define OFF_IDX  4096                      // int idxTable[540672]
#define OFF_CNT  (4096 + 2162688 + 1024)   // float cnt[2][65536]

// ---------------------------------------------------------------------------
// Kernel 1: replicate the numpy float32 preprocessing exactly.
//  - rs computed in f64 (python scalars), cast to f32
//  - K = intrinsics * rs[:,None] in f32
//  - Kinv: adjugate in f32. For this K every op is an exact pow2 scaling
//    (det = 1024), so this matches LAPACK sgetri bit-exactly.
//  - dbins: np.linspace in f64 (1 + i*(59/63), endpoint forced to 60.0),
//    then cast to f32.
// ---------------------------------------------------------------------------
__global__ void k_setup(const float* __restrict__ intr, const float* __restrict__ extr,
                        const int* __restrict__ p_imgh, const int* __restrict__ p_imgw,
                        float* __restrict__ Ki, float* __restrict__ db) {
    int i = threadIdx.x;
    if (i < Dc) {
        double step = 59.0 / 63.0;
        double v = 1.0 + (double)i * step;
        db[i] = (i == Dc - 1) ? 60.0f : (float)v;   // np.linspace sets y[-1]=stop
    }
    if (i >= BNc) return;
    double img_h = (double)p_imgh[0];
    double img_w = (double)p_imgw[0];
    double scale_x = (double)Wc / (img_w / 16.0);
    double scale_y = (double)Hc / (img_h / 16.0);
    float rs0 = (float)(16.0 / scale_x);
    float rs1 = (float)(16.0 / scale_y);
    float rs2 = 1.0f;
    const float* K = intr + i * 9;
    float k0 = __fmul_rn(K[0], rs0), k1 = __fmul_rn(K[1], rs0), k2 = __fmul_rn(K[2], rs0);
    float k3 = __fmul_rn(K[3], rs1), k4 = __fmul_rn(K[4], rs1), k5 = __fmul_rn(K[5], rs1);
    float k6 = __fmul_rn(K[6], rs2), k7 = __fmul_rn(K[7], rs2), k8 = __fmul_rn(K[8], rs2);
    float c0 = __fsub_rn(__fmul_rn(k4,k8), __fmul_rn(k5,k7));
    float c1 = __fsub_rn(__fmul_rn(k3,k8), __fmul_rn(k5,k6));
    float c2 = __fsub_rn(__fmul_rn(k3,k7), __fmul_rn(k4,k6));
    float det = __fadd_rn(__fsub_rn(__fmul_rn(k0,c0), __fmul_rn(k1,c1)), __fmul_rn(k2,c2));
    float* o = Ki + i * 9;
    o[0] = __fdiv_rn(c0, det);
    o[1] = __fdiv_rn(__fsub_rn(__fmul_rn(k2,k7), __fmul_rn(k1,k8)), det);
    o[2] = __fdiv_rn(__fsub_rn(__fmul_rn(k1,k5), __fmul_rn(k2,k4)), det);
    o[3] = __fdiv_rn(__fsub_rn(__fmul_rn(k5,k6), __fmul_rn(k3,k8)), det);
    o[4] = __fdiv_rn(__fsub_rn(__fmul_rn(k0,k8), __fmul_rn(k2,k6)), det);
    o[5] = __fdiv_rn(__fsub_rn(__fmul_rn(k2,k3), __fmul_rn(k0,k5)), det);
    o[6] = c2;  // (k3*k7-k4*k6)
    o[6] = __fdiv_rn(o[6], det);
    o[7] = __fdiv_rn(__fsub_rn(__fmul_rn(k1,k6), __fmul_rn(k0,k7)), det);
    o[8] = __fdiv_rn(__fsub_rn(__fmul_rn(k0,k4), __fmul_rn(k1,k3)), det);
}

// ---------------------------------------------------------------------------
// Kernel 2: classify each frustum point -> BEV cell index (or -1), f32 chain
// replicating numpy exactly (fmaf chains = einsum's contracted accum loops;
// separate rounded add for +t; truncating int cast).
// ---------------------------------------------------------------------------
__global__ __launch_bounds__(256) void k_classify(const float* __restrict__ Ki_all,
                                                  const float* __restrict__ db,
                                                  const float* __restrict__ extr,
                                                  int* __restrict__ idxT,
                                                  float* __restrict__ cnt) {
    int gid = blockIdx.x * 256 + threadIdx.x;
    if (gid >= NPTS) return;
    int p   = gid % HWc;      // h*W + w
    int tmp = gid / HWc;      // (b*N+n)*D + d
    int d   = tmp % Dc;
    int bn  = tmp / Dc;
    int b   = bn / Nc;
    int w = p % Wc, h = p / Wc;
    float dd = db[d];
    float ud = __fmul_rn((float)w, dd);
    float vd = __fmul_rn((float)h, dd);
    const float* Ki = Ki_all + bn * 9;
    float pcx = fmaf(Ki[2], dd, fmaf(Ki[1], vd, __fmul_rn(Ki[0], ud)));
    float pcy = fmaf(Ki[5], dd, fmaf(Ki[4], vd, __fmul_rn(Ki[3], ud)));
    float pcz = fmaf(Ki[8], dd, fmaf(Ki[7], vd, __fmul_rn(Ki[6], ud)));
    const float* E = extr + bn * 16;
    float px = __fadd_rn(fmaf(E[2],  pcz, fmaf(E[1], pcy, __fmul_rn(E[0], pcx))), E[3]);
    float py = __fadd_rn(fmaf(E[6],  pcz, fmaf(E[5], pcy, __fmul_rn(E[4], pcx))), E[7]);
    float pz = __fadd_rn(fmaf(E[10], pcz, fmaf(E[9], pcy, __fmul_rn(E[8], pcx))), E[11]);
    float fx = __fdiv_rn(__fsub_rn(px, -51.2f), 0.4f);
    float fy = __fdiv_rn(__fsub_rn(py, -51.2f), 0.4f);
    int xi = (int)fx;          // trunc toward zero == astype(int32)
    int yi = (int)fy;
    bool valid = (xi >= 0) && (xi < BEV_W) && (yi >= 0) && (yi < BEV_H)
              && (pz >= -5.0f) && (pz <= 3.0f);
    int cell = valid ? (yi * BEV_W + xi) : -1;
    idxT[gid] = cell;
    if (valid) atomicAdd(&cnt[b * BEV_HW + cell], 1.0f);
}

// ---------------------------------------------------------------------------
// Kernel 3: scatter. One block per (b,n,d). Stage the 704 depth weights and
// cell indices in LDS, then loop channels with coalesced feat reads and
// atomicAdd into out[b, c, cell].
// ---------------------------------------------------------------------------
__global__ __launch_bounds__(256) void k_scatter(const float* __restrict__ feat,
                                                 const float* __restrict__ depth,
                                                 const int* __restrict__ idxT,
                                                 float* __restrict__ out) {
    __shared__ float s_dw[HWc];
    __shared__ int   s_idx[HWc];
    int blk = blockIdx.x;          // (b*N+n)*D + d
    int bn  = blk / Dc;
    int b   = bn / Nc;
    int tid = threadIdx.x;
    const float* dp = depth + (size_t)blk * HWc;
    const int*   ip = idxT  + (size_t)blk * HWc;
    for (int p = tid; p < HWc; p += 256) { s_dw[p] = dp[p]; s_idx[p] = ip[p]; }
    __syncthreads();
    const float* fb = feat + (size_t)bn * Cc * HWc;
    float*       ob = out  + (size_t)b  * Cc * BEV_HW;
    for (int c = 0; c < Cc; c++) {
        const float* f = fb + (size_t)c * HWc;
        float*       o = ob + (size_t)c * BEV_HW;
        for (int p = tid; p < HWc; p += 256) {
            int cell = s_idx[p];
            if (cell >= 0) atomicAdd(&o[cell], __fmul_rn(f[p], s_dw[p]));
        }
    }
}

// ---------------------------------------------------------------------------
// Kernel 4: normalize out[b,c,q] /= (cnt[b,q] + 1e-5), vectorized float4.
// ---------------------------------------------------------------------------
__global__ __launch_bounds__(256) void k_norm(float* __restrict__ out,
                                              const float* __restrict__ cnt) {
    int i = blockIdx.x * 256 + threadIdx.x;        // over float4s
    const int total = Bc * Cc * BEV_HW / 4;
    if (i >= total) return;
    int q = i % (BEV_HW / 4);
    int b = i / (Cc * BEV_HW / 4);
    float4 v = ((float4*)out)[i];
    float4 cv = ((const float4*)cnt)[b * (BEV_HW / 4) + q];
    v.x = __fdiv_rn(v.x, __fadd_rn(cv.x, 1e-5f));
    v.y = __fdiv_rn(v.y, __fadd_rn(cv.y, 1e-5f));
    v.z = __fdiv_rn(v.z, __fadd_rn(cv.z, 1e-5f));
    v.w = __fdiv_rn(v.w, __fadd_rn(cv.w, 1e-5f));
    ((float4*)out)[i] = v;
}

extern "C" void kernel_launch(void* const* d_in, const int* in_sizes, int n_in,
                              void* d_out, int out_size, void* d_ws, size_t ws_size,
                              hipStream_t stream) {
    const float* feat  = (const float*)d_in[0];
    const float* depth = (const float*)d_in[1];
    const float* intr  = (const float*)d_in[2];
    const float* extr  = (const float*)d_in[3];
    const int*   imh   = (const int*)d_in[4];
    const int*   imw   = (const int*)d_in[5];
    float* out = (float*)d_out;
    char*  ws  = (char*)d_ws;
    float* Ki   = (float*)(ws + OFF_KI);
    float* db   = (float*)(ws + OFF_DB);
    int*   idxT = (int*)(ws + OFF_IDX);
    float* cnt  = (float*)(ws + OFF_CNT);

    hipMemsetAsync(out, 0, (size_t)out_size * sizeof(float), stream);
    hipMemsetAsync(cnt, 0, (size_t)Bc * BEV_HW * sizeof(float), stream);

    k_setup<<<1, 64, 0, stream>>>(intr, extr, imh, imw, Ki, db);
    k_classify<<<(NPTS + 255) / 256, 256, 0, stream>>>(Ki, db, extr, idxT, cnt);
    k_scatter<<<Bc * Nc * Dc, 256, 0, stream>>>(feat, depth, idxT, out);
    k_norm<<<(Bc * Cc * BEV_HW / 4 + 255) / 256, 256, 0, stream>>>(out, cnt);
}

// Round 3
// 206.632 us; speedup vs baseline: 11.2796x; 11.2796x over previous
//
#include <hip/hip_runtime.h>
#include <hip/hip_bf16.h>

// Problem constants (from reference setup_inputs)
#define Bc 2
#define Nc 6
#define Cc 128
#define Hc 16
#define Wc 44
#define Dc 64
#define HWc (Hc*Wc)          // 704
#define BNc (Bc*Nc)          // 12
#define NRAY (Nc*HWc)        // 4224 rays per batch
#define NPTS (Bc*Nc*Dc*HWc)  // 540672
#define BEV_W 256
#define BEV_H 256
#define BEV_HW (BEV_W*BEV_H) // 65536
#define NSEG (Bc*BEV_HW)     // 131072
#define GT 16                // cells per gather block

// ---------------- workspace layout (bytes) ----------------
#define OFF_KI   0                 // float Kinv[12][9]
#define OFF_DB   512               // float dbins[64]
#define OFF_IDX  1024              // int idxT[NPTS]            2162688
#define OFF_CNTI (OFF_IDX + 2162688)        // int cnt[NSEG]    524288
#define OFF_OFFS (OFF_CNTI + 524288)        // int offs[NSEG]   524288
#define OFF_FILL (OFF_OFFS + 524288)        // int fill[NSEG]   524288
#define OFF_BSUM (OFF_FILL + 524288)        // int bsum[512]    2048
#define OFF_ER   (OFF_BSUM + 2048)          // int er[NPTS]     2162688
#define OFF_EW   (OFF_ER + 2162688)         // float ew[NPTS]   2162688
#define OFF_FT   (OFF_EW + 2162688)         // float ft[B][NRAY][C] 4325376
#define WS_NEED  (OFF_FT + 4325376)         // ~12.4 MB
// fallback (round-2) layout
#define OFF_FCNT OFF_CNTI                   // float cnt[2][BEV_HW]

// ---------------------------------------------------------------------------
// Kernel 1: replicate the numpy float32 preprocessing exactly (see round 2).
// ---------------------------------------------------------------------------
__global__ void k_setup(const float* __restrict__ intr, const float* __restrict__ extr,
                        const int* __restrict__ p_imgh, const int* __restrict__ p_imgw,
                        float* __restrict__ Ki, float* __restrict__ db) {
    int i = threadIdx.x;
    if (i < Dc) {
        double step = 59.0 / 63.0;
        double v = 1.0 + (double)i * step;
        db[i] = (i == Dc - 1) ? 60.0f : (float)v;   // np.linspace endpoint = stop
    }
    if (i >= BNc) return;
    double img_h = (double)p_imgh[0];
    double img_w = (double)p_imgw[0];
    double scale_x = (double)Wc / (img_w / 16.0);
    double scale_y = (double)Hc / (img_h / 16.0);
    float rs0 = (float)(16.0 / scale_x);
    float rs1 = (float)(16.0 / scale_y);
    float rs2 = 1.0f;
    const float* K = intr + i * 9;
    float k0 = __fmul_rn(K[0], rs0), k1 = __fmul_rn(K[1], rs0), k2 = __fmul_rn(K[2], rs0);
    float k3 = __fmul_rn(K[3], rs1), k4 = __fmul_rn(K[4], rs1), k5 = __fmul_rn(K[5], rs1);
    float k6 = __fmul_rn(K[6], rs2), k7 = __fmul_rn(K[7], rs2), k8 = __fmul_rn(K[8], rs2);
    float c0 = __fsub_rn(__fmul_rn(k4,k8), __fmul_rn(k5,k7));
    float c1 = __fsub_rn(__fmul_rn(k3,k8), __fmul_rn(k5,k6));
    float c2 = __fsub_rn(__fmul_rn(k3,k7), __fmul_rn(k4,k6));
    float det = __fadd_rn(__fsub_rn(__fmul_rn(k0,c0), __fmul_rn(k1,c1)), __fmul_rn(k2,c2));
    float* o = Ki + i * 9;
    o[0] = __fdiv_rn(c0, det);
    o[1] = __fdiv_rn(__fsub_rn(__fmul_rn(k2,k7), __fmul_rn(k1,k8)), det);
    o[2] = __fdiv_rn(__fsub_rn(__fmul_rn(k1,k5), __fmul_rn(k2,k4)), det);
    o[3] = __fdiv_rn(__fsub_rn(__fmul_rn(k5,k6), __fmul_rn(k3,k8)), det);
    o[4] = __fdiv_rn(__fsub_rn(__fmul_rn(k0,k8), __fmul_rn(k2,k6)), det);
    o[5] = __fdiv_rn(__fsub_rn(__fmul_rn(k2,k3), __fmul_rn(k0,k5)), det);
    o[6] = __fdiv_rn(c2, det);
    o[7] = __fdiv_rn(__fsub_rn(__fmul_rn(k1,k6), __fmul_rn(k0,k7)), det);
    o[8] = __fdiv_rn(__fsub_rn(__fmul_rn(k0,k4), __fmul_rn(k1,k3)), det);
}

// ---------------------------------------------------------------------------
// classify device helper: numpy-f32-exact chain  -> cell or -1
// ---------------------------------------------------------------------------
__device__ __forceinline__ int classify_point(int gid, const float* Ki_all,
                                              const float* db, const float* extr) {
    int p   = gid % HWc;
    int tmp = gid / HWc;
    int d   = tmp % Dc;
    int bn  = tmp / Dc;
    int w = p % Wc, h = p / Wc;
    float dd = db[d];
    float ud = __fmul_rn((float)w, dd);
    float vd = __fmul_rn((float)h, dd);
    const float* Ki = Ki_all + bn * 9;
    float pcx = fmaf(Ki[2], dd, fmaf(Ki[1], vd, __fmul_rn(Ki[0], ud)));
    float pcy = fmaf(Ki[5], dd, fmaf(Ki[4], vd, __fmul_rn(Ki[3], ud)));
    float pcz = fmaf(Ki[8], dd, fmaf(Ki[7], vd, __fmul_rn(Ki[6], ud)));
    const float* E = extr + bn * 16;
    float px = __fadd_rn(fmaf(E[2],  pcz, fmaf(E[1], pcy, __fmul_rn(E[0], pcx))), E[3]);
    float py = __fadd_rn(fmaf(E[6],  pcz, fmaf(E[5], pcy, __fmul_rn(E[4], pcx))), E[7]);
    float pz = __fadd_rn(fmaf(E[10], pcz, fmaf(E[9], pcy, __fmul_rn(E[8], pcx))), E[11]);
    float fx = __fdiv_rn(__fsub_rn(px, -51.2f), 0.4f);
    float fy = __fdiv_rn(__fsub_rn(py, -51.2f), 0.4f);
    int xi = (int)fx;
    int yi = (int)fy;
    bool valid = (xi >= 0) && (xi < BEV_W) && (yi >= 0) && (yi < BEV_H)
              && (pz >= -5.0f) && (pz <= 3.0f);
    return valid ? (yi * BEV_W + xi) : -1;
}

// ---------------------------------------------------------------------------
// Kernel 2: classify + per-(b,cell) int count
// ---------------------------------------------------------------------------
__global__ __launch_bounds__(256) void k_count(const float* __restrict__ Ki_all,
                                               const float* __restrict__ db,
                                               const float* __restrict__ extr,
                                               int* __restrict__ idxT,
                                               int* __restrict__ cntArr) {
    int gid = blockIdx.x * 256 + threadIdx.x;
    if (gid >= NPTS) return;
    int cell = classify_point(gid, Ki_all, db, extr);
    idxT[gid] = cell;
    if (cell >= 0) {
        int b = gid / (Nc * Dc * HWc);
        atomicAdd(&cntArr[b * BEV_HW + cell], 1);
    }
}

// ---------------------------------------------------------------------------
// Hierarchical exclusive scan over NSEG=131072 ints
// ---------------------------------------------------------------------------
__global__ __launch_bounds__(256) void k_scan1(const int* __restrict__ cntArr,
                                               int* __restrict__ offs,
                                               int* __restrict__ bsum) {
    __shared__ int s[256];
    int tid = threadIdx.x;
    int g = blockIdx.x * 256 + tid;
    int v = cntArr[g];
    s[tid] = v; __syncthreads();
    for (int st = 1; st < 256; st <<= 1) {
        int t = (tid >= st) ? s[tid - st] : 0;
        __syncthreads();
        s[tid] += t;
        __syncthreads();
    }
    offs[g] = s[tid] - v;
    if (tid == 255) bsum[blockIdx.x] = s[255];
}

__global__ __launch_bounds__(512) void k_scan2(int* __restrict__ bsum) {
    __shared__ int s[512];
    int tid = threadIdx.x;
    int v = bsum[tid];
    s[tid] = v; __syncthreads();
    for (int st = 1; st < 512; st <<= 1) {
        int t = (tid >= st) ? s[tid - st] : 0;
        __syncthreads();
        s[tid] += t;
        __syncthreads();
    }
    bsum[tid] = s[tid] - v;   // exclusive
}

__global__ __launch_bounds__(256) void k_scan3(int* __restrict__ offs,
                                               const int* __restrict__ bsum,
                                               int* __restrict__ fill) {
    int g = blockIdx.x * 256 + threadIdx.x;
    int o = offs[g] + bsum[blockIdx.x >> 0];  // 256 elems/block → block i covers bsum[i]
    // note: blockIdx.x in [0,512), same partitioning as k_scan1
    offs[g] = o;
    fill[g] = o;
}

// ---------------------------------------------------------------------------
// Kernel 3: fill entry lists (ray id + depth weight) per (b,cell) segment
// ---------------------------------------------------------------------------
__global__ __launch_bounds__(256) void k_fill(const int* __restrict__ idxT,
                                              const float* __restrict__ depth,
                                              int* __restrict__ fill,
                                              int* __restrict__ er,
                                              float* __restrict__ ew) {
    int gid = blockIdx.x * 256 + threadIdx.x;
    if (gid >= NPTS) return;
    int cell = idxT[gid];
    if (cell < 0) return;
    int p   = gid % HWc;
    int bn  = gid / (Dc * HWc);
    int b   = bn / Nc;
    int pos = atomicAdd(&fill[b * BEV_HW + cell], 1);
    er[pos] = (bn % Nc) * HWc + p;
    ew[pos] = depth[gid];
}

// ---------------------------------------------------------------------------
// Kernel 4: transpose feat [bn][c][hw] -> ft[b][ray][c] (ray = n*HWc+hw)
// ---------------------------------------------------------------------------
__global__ __launch_bounds__(256) void k_transpose(const float* __restrict__ feat,
                                                   float* __restrict__ ft) {
    __shared__ float buf[Cc * 17];   // [c][hw16] padded: stride 17, conflict-free
    int bn   = blockIdx.x / (HWc / 16);
    int tile = blockIdx.x % (HWc / 16);
    int tid = threadIdx.x;
    const float* fb = feat + (size_t)bn * Cc * HWc + tile * 16;
    for (int i = tid; i < Cc * 16; i += 256) {
        int c = i >> 4, hw = i & 15;
        buf[c * 17 + hw] = fb[c * HWc + hw];
    }
    __syncthreads();
    float* ob = ft + ((size_t)bn * HWc + tile * 16) * Cc;
    for (int i = tid; i < 16 * Cc; i += 256) {
        int r = i >> 7, c = i & 127;
        ob[(size_t)r * Cc + c] = buf[c * 17 + r];
    }
}

// ---------------------------------------------------------------------------
// Kernel 5: gather. Block = (b, tile of GT cells). Two 128-thread groups,
// each group handles one cell at a time: c-parallel coalesced ft reads,
// broadcast entry scalars, sequential FMA. Normalization fused.
// ---------------------------------------------------------------------------
__global__ __launch_bounds__(256) void k_gather(const float* __restrict__ ft,
                                                const int* __restrict__ er,
                                                const float* __restrict__ ew,
                                                const int* __restrict__ cntArr,
                                                const int* __restrict__ offs,
                                                float* __restrict__ out) {
    __shared__ float res[Cc * (GT + 1)];
    int blk  = blockIdx.x;
    int tile = blk % (BEV_HW / GT);
    int b    = blk / (BEV_HW / GT);
    int cell0 = tile * GT;
    int tid = threadIdx.x;
    int c   = tid & 127;
    int grp = tid >> 7;
    const float* ftb = ft + (size_t)b * NRAY * Cc;
    for (int g = grp; g < GT; g += 2) {
        int seg = b * BEV_HW + cell0 + g;
        int n = cntArr[seg];
        int o = offs[seg];
        float acc = 0.0f;
        int e = 0;
        for (; e + 4 <= n; e += 4) {
            int   r0 = er[o+e],   r1 = er[o+e+1], r2 = er[o+e+2], r3 = er[o+e+3];
            float w0 = ew[o+e],   w1 = ew[o+e+1], w2 = ew[o+e+2], w3 = ew[o+e+3];
            float f0 = ftb[(size_t)r0 * Cc + c];
            float f1 = ftb[(size_t)r1 * Cc + c];
            float f2 = ftb[(size_t)r2 * Cc + c];
            float f3 = ftb[(size_t)r3 * Cc + c];
            acc = fmaf(w0, f0, acc);
            acc = fmaf(w1, f1, acc);
            acc = fmaf(w2, f2, acc);
            acc = fmaf(w3, f3, acc);
        }
        for (; e < n; e++) {
            acc = fmaf(ew[o+e], ftb[(size_t)er[o+e] * Cc + c], acc);
        }
        res[c * (GT + 1) + g] = __fdiv_rn(acc, __fadd_rn((float)n, 1e-5f));
    }
    __syncthreads();
    float* ob = out + (size_t)b * Cc * BEV_HW + cell0;
    for (int i = tid; i < Cc * GT; i += 256) {
        int cc = i / GT, g = i % GT;
        ob[(size_t)cc * BEV_HW + g] = res[cc * (GT + 1) + g];
    }
}

// ======================= fallback (round-2) kernels =========================
__global__ __launch_bounds__(256) void k_classifyF(const float* __restrict__ Ki_all,
                                                   const float* __restrict__ db,
                                                   const float* __restrict__ extr,
                                                   int* __restrict__ idxT,
                                                   float* __restrict__ cnt) {
    int gid = blockIdx.x * 256 + threadIdx.x;
    if (gid >= NPTS) return;
    int cell = classify_point(gid, Ki_all, db, extr);
    idxT[gid] = cell;
    if (cell >= 0) {
        int b = gid / (Nc * Dc * HWc);
        atomicAdd(&cnt[b * BEV_HW + cell], 1.0f);
    }
}

__global__ __launch_bounds__(256) void k_scatterF(const float* __restrict__ feat,
                                                  const float* __restrict__ depth,
                                                  const int* __restrict__ idxT,
                                                  float* __restrict__ out) {
    __shared__ float s_dw[HWc];
    __shared__ int   s_idx[HWc];
    int blk = blockIdx.x;
    int bn  = blk / Dc;
    int b   = bn / Nc;
    int tid = threadIdx.x;
    const float* dp = depth + (size_t)blk * HWc;
    const int*   ip = idxT  + (size_t)blk * HWc;
    for (int p = tid; p < HWc; p += 256) { s_dw[p] = dp[p]; s_idx[p] = ip[p]; }
    __syncthreads();
    const float* fb = feat + (size_t)bn * Cc * HWc;
    float*       ob = out  + (size_t)b  * Cc * BEV_HW;
    for (int c = 0; c < Cc; c++) {
        const float* f = fb + (size_t)c * HWc;
        float*       o = ob + (size_t)c * BEV_HW;
        for (int p = tid; p < HWc; p += 256) {
            int cell = s_idx[p];
            if (cell >= 0) atomicAdd(&o[cell], __fmul_rn(f[p], s_dw[p]));
        }
    }
}

__global__ __launch_bounds__(256) void k_normF(float* __restrict__ out,
                                               const float* __restrict__ cnt) {
    int i = blockIdx.x * 256 + threadIdx.x;
    const int total = Bc * Cc * BEV_HW / 4;
    if (i >= total) return;
    int q = i % (BEV_HW / 4);
    int b = i / (Cc * BEV_HW / 4);
    float4 v = ((float4*)out)[i];
    float4 cv = ((const float4*)cnt)[b * (BEV_HW / 4) + q];
    v.x = __fdiv_rn(v.x, __fadd_rn(cv.x, 1e-5f));
    v.y = __fdiv_rn(v.y, __fadd_rn(cv.y, 1e-5f));
    v.z = __fdiv_rn(v.z, __fadd_rn(cv.z, 1e-5f));
    v.w = __fdiv_rn(v.w, __fadd_rn(cv.w, 1e-5f));
    ((float4*)out)[i] = v;
}

// ===========================================================================
extern "C" void kernel_launch(void* const* d_in, const int* in_sizes, int n_in,
                              void* d_out, int out_size, void* d_ws, size_t ws_size,
                              hipStream_t stream) {
    const float* feat  = (const float*)d_in[0];
    const float* depth = (const float*)d_in[1];
    const float* intr  = (const float*)d_in[2];
    const float* extr  = (const float*)d_in[3];
    const int*   imh   = (const int*)d_in[4];
    const int*   imw   = (const int*)d_in[5];
    float* out = (float*)d_out;
    char*  ws  = (char*)d_ws;
    float* Ki   = (float*)(ws + OFF_KI);
    float* db   = (float*)(ws + OFF_DB);
    int*   idxT = (int*)(ws + OFF_IDX);

    if (ws_size >= (size_t)WS_NEED) {
        int*   cntA = (int*)(ws + OFF_CNTI);
        int*   offs = (int*)(ws + OFF_OFFS);
        int*   fill = (int*)(ws + OFF_FILL);
        int*   bsum = (int*)(ws + OFF_BSUM);
        int*   er   = (int*)(ws + OFF_ER);
        float* ew   = (float*)(ws + OFF_EW);
        float* ft   = (float*)(ws + OFF_FT);

        hipMemsetAsync(cntA, 0, (size_t)NSEG * sizeof(int), stream);
        k_setup<<<1, 64, 0, stream>>>(intr, extr, imh, imw, Ki, db);
        k_count<<<(NPTS + 255) / 256, 256, 0, stream>>>(Ki, db, extr, idxT, cntA);
        k_scan1<<<NSEG / 256, 256, 0, stream>>>(cntA, offs, bsum);
        k_scan2<<<1, 512, 0, stream>>>(bsum);
        k_scan3<<<NSEG / 256, 256, 0, stream>>>(offs, bsum, fill);
        k_fill<<<(NPTS + 255) / 256, 256, 0, stream>>>(idxT, depth, fill, er, ew);
        k_transpose<<<BNc * (HWc / 16), 256, 0, stream>>>(feat, ft);
        k_gather<<<Bc * (BEV_HW / GT), 256, 0, stream>>>(ft, er, ew, cntA, offs, out);
    } else {
        float* cnt = (float*)(ws + OFF_FCNT);
        hipMemsetAsync(out, 0, (size_t)out_size * sizeof(float), stream);
        hipMemsetAsync(cnt, 0, (size_t)Bc * BEV_HW * sizeof(float), stream);
        k_setup<<<1, 64, 0, stream>>>(intr, extr, imh, imw, Ki, db);
        k_classifyF<<<(NPTS + 255) / 256, 256, 0, stream>>>(Ki, db, extr, idxT, cnt);
        k_scatterF<<<Bc * Nc * Dc, 256, 0, stream>>>(feat, depth, idxT, out);
        k_normF<<<(Bc * Cc * BEV_HW / 4 + 255) / 256, 256, 0, stream>>>(out, cnt);
    }
}